// Round 2
// baseline (641.970 us; speedup 1.0000x reference)
//
#include <hip/hip_runtime.h>
#include <hip/hip_bf16.h>

#define B_ 8
#define N_ 1024
#define D_ 1024
#define H_ 16
#define FF_ 4096
#define TOK_ (B_*N_)

typedef __attribute__((ext_vector_type(8))) short bf16x8;
typedef __attribute__((ext_vector_type(4))) float f32x4;

typedef const __attribute__((address_space(1))) void* gc_ptr;
typedef __attribute__((address_space(3))) void* lp_ptr;

// float -> bf16 bits, round-to-nearest-even (values are finite; no NaN path needed)
__device__ __forceinline__ short f2bf(float f) {
    unsigned u = __builtin_bit_cast(unsigned, f);
    u = (u + 0x7FFFu + ((u >> 16) & 1u)) >> 16;
    return (short)u;
}

// ---------------------------------------------------------------------------
// fp32 -> bf16 convert (weights), 4 elements/thread
// ---------------------------------------------------------------------------
__global__ __launch_bounds__(256)
void cvt_bf16(const float* __restrict__ in, short* __restrict__ outp) {
    const size_t i = ((size_t)blockIdx.x * 256 + threadIdx.x) * 4;
    const float4 v = *(const float4*)(in + i);
    short4 o;
    o.x = f2bf(v.x); o.y = f2bf(v.y); o.z = f2bf(v.z); o.w = f2bf(v.w);
    *(short4*)(outp + i) = o;
}

// ---------------------------------------------------------------------------
// LayerNorm over D=1024: one block per row, 256 threads, 4 floats each.
// Writes fp32 (residual path) and bf16 (GEMM input).
// ---------------------------------------------------------------------------
__global__ __launch_bounds__(256)
void ln_kernel(const float* __restrict__ in, const float* __restrict__ w,
               const float* __restrict__ bi, float* __restrict__ o32,
               short* __restrict__ obf) {
    const int row = blockIdx.x;
    const int tid = threadIdx.x;
    const float4 v = ((const float4*)(in + (size_t)row * D_))[tid];
    float s = v.x + v.y + v.z + v.w;
    float q = v.x * v.x + v.y * v.y + v.z * v.z + v.w * v.w;
#pragma unroll
    for (int off = 1; off < 64; off <<= 1) {
        s += __shfl_xor(s, off);
        q += __shfl_xor(q, off);
    }
    __shared__ float ss[4], sq[4];
    const int wave = tid >> 6, lane = tid & 63;
    if (lane == 0) { ss[wave] = s; sq[wave] = q; }
    __syncthreads();
    s = ss[0] + ss[1] + ss[2] + ss[3];
    q = sq[0] + sq[1] + sq[2] + sq[3];
    const float mu = s * (1.f / D_);
    const float var = q * (1.f / D_) - mu * mu;
    const float rs = rsqrtf(var + 1e-5f);
    const float4 wv = ((const float4*)w)[tid];
    const float4 bv = ((const float4*)bi)[tid];
    float4 o;
    o.x = (v.x - mu) * rs * wv.x + bv.x;
    o.y = (v.y - mu) * rs * wv.y + bv.y;
    o.z = (v.z - mu) * rs * wv.z + bv.z;
    o.w = (v.w - mu) * rs * wv.w + bv.w;
    ((float4*)(o32 + (size_t)row * D_))[tid] = o;
    short4 ob;
    ob.x = f2bf(o.x); ob.y = f2bf(o.y); ob.z = f2bf(o.z); ob.w = f2bf(o.w);
    *(short4*)(obf + (size_t)row * D_ + tid * 4) = ob;
}

// ---------------------------------------------------------------------------
// GEMM: C[M,Nc] = A[M,K] @ Bw[Nc,K]^T  (both bf16, K-contiguous) — m97 structure
// 128x128 tile, BK=32, 4 waves each owning 64x64 (4x4 of 16x16x32 MFMA).
// MODE 0: scatter to q/k/v [3][B,H,N,64] bf16 (no bias)
// MODE 1: out_f32 = acc + bias[col] + res[row,col]
// MODE 2: out_bf16 = gelu_exact(acc + bias[col])
// ---------------------------------------------------------------------------
template<int MODE>
__global__ __launch_bounds__(256, 2)
void gemm_bt(const short* __restrict__ A, const short* __restrict__ Bw,
             const float* __restrict__ bias, const float* __restrict__ res,
             void* __restrict__ outp, int M, int Nc, int K) {
    const int tid  = threadIdx.x;
    const int wave = tid >> 6;
    const int lane = tid & 63;
    const int m16  = lane & 15;
    const int quad = lane >> 4;
    const int wrow = (wave >> 1) * 64;
    const int wcol = (wave & 1) * 64;
    const int rowBase = blockIdx.y * 128;
    const int colBase = blockIdx.x * 128;

    __shared__ short sA[128 * 32];
    __shared__ short sB[128 * 32];

    f32x4 acc[4][4];
#pragma unroll
    for (int i = 0; i < 4; ++i)
#pragma unroll
        for (int j = 0; j < 4; ++j)
            acc[i][j] = {0.f, 0.f, 0.f, 0.f};

    const int r16 = lane >> 2;   // row within 16-row staging group
    const int c4  = lane & 3;    // 16B chunk within 64B row

    for (int kt = 0; kt < K; kt += 32) {
        // async global->LDS staging, width 16; LDS dest is wave-uniform base + lane*16
#pragma unroll
        for (int rep = 0; rep < 2; ++rep) {
            const int tr = rep * 64 + wave * 16;
            const short* ga = A  + (size_t)(rowBase + tr + r16) * K + kt + c4 * 8;
            const short* gb = Bw + (size_t)(colBase + tr + r16) * K + kt + c4 * 8;
            __builtin_amdgcn_global_load_lds((gc_ptr)ga, (lp_ptr)(sA + tr * 32), 16, 0, 0);
            __builtin_amdgcn_global_load_lds((gc_ptr)gb, (lp_ptr)(sB + tr * 32), 16, 0, 0);
        }
        asm volatile("s_waitcnt vmcnt(0)" ::: "memory");
        __syncthreads();

        bf16x8 af[4], bfr[4];
#pragma unroll
        for (int i = 0; i < 4; ++i)
            af[i] = *(const bf16x8*)(sA + (wrow + i * 16 + m16) * 32 + quad * 8);
#pragma unroll
        for (int j = 0; j < 4; ++j)
            bfr[j] = *(const bf16x8*)(sB + (wcol + j * 16 + m16) * 32 + quad * 8);
#pragma unroll
        for (int i = 0; i < 4; ++i)
#pragma unroll
            for (int j = 0; j < 4; ++j)
                acc[i][j] = __builtin_amdgcn_mfma_f32_16x16x32_bf16(af[i], bfr[j], acc[i][j], 0, 0, 0);
        __syncthreads();
    }

    // epilogue: C/D layout col = lane&15, row = quad*4 + r  (m89-verified)
#pragma unroll
    for (int i = 0; i < 4; ++i) {
#pragma unroll
        for (int j = 0; j < 4; ++j) {
            const int col = colBase + wcol + j * 16 + m16;
#pragma unroll
            for (int r = 0; r < 4; ++r) {
                const int row = rowBase + wrow + i * 16 + quad * 4 + r;
                const float val = acc[i][j][r];
                if (MODE == 0) {
                    const int ci = col >> 10, hh = (col >> 6) & 15, dd = col & 63;
                    const int bb = row >> 10, nn = row & 1023;
                    ((short*)outp)[(size_t)ci * ((size_t)TOK_ * 1024) +
                                   ((size_t)((bb * H_ + hh) * N_ + nn)) * 64 + dd] = f2bf(val);
                } else if (MODE == 1) {
                    ((float*)outp)[(size_t)row * Nc + col] =
                        val + bias[col] + res[(size_t)row * Nc + col];
                } else {
                    const float t = val + bias[col];
                    const float g = 0.5f * t * (1.f + erff(t * 0.70710678118654752f));
                    ((short*)outp)[(size_t)row * Nc + col] = f2bf(g);
                }
            }
        }
    }
}

// ---------------------------------------------------------------------------
// Flash attention: block = (64 q-rows, h, b), 4 waves x 16 q-rows.
// K-tiles of 32, online softmax, P via per-wave LDS (C-layout -> A-layout).
// Mask: logits = (q.k + (-1e9 * ids[key])) * 0.125, softmax over keys.
// ---------------------------------------------------------------------------
__global__ __launch_bounds__(256, 2)
void attn_kernel(const short* __restrict__ q, const short* __restrict__ k,
                 const short* __restrict__ v, const int* __restrict__ ids,
                 short* __restrict__ outp) {
    const int tid  = threadIdx.x;
    const int wave = tid >> 6;
    const int lane = tid & 63;
    const int m    = lane & 15;
    const int quad = lane >> 4;
    const int b  = blockIdx.z;
    const int h  = blockIdx.y;
    const int q0 = blockIdx.x * 64;
    const size_t bh = ((size_t)b * H_ + h) * N_;

    __shared__ short Kt[32 * 72];       // [key][dh], padded rows (144B, 16B-aligned)
    __shared__ short Vt[64 * 40];       // [dh][key], padded rows (80B)
    __shared__ short Pl[4][16 * 40];    // per-wave P tile [qrow][key], padded

    // Q A-frags (two dh-chunks of 32)
    bf16x8 aq0, aq1;
    {
        const short* qp = q + (bh + q0 + wave * 16 + m) * 64;
        aq0 = *(const bf16x8*)(qp + quad * 8);
        aq1 = *(const bf16x8*)(qp + 32 + quad * 8);
    }

    float mrow[4], lrow[4];
    f32x4 o[4];
#pragma unroll
    for (int r = 0; r < 4; ++r) { mrow[r] = -INFINITY; lrow[r] = 0.f; }
#pragma unroll
    for (int j = 0; j < 4; ++j) o[j] = {0.f, 0.f, 0.f, 0.f};

    const int* idrow = ids + b * N_;

    for (int kt0 = 0; kt0 < N_; kt0 += 32) {
        __syncthreads();   // protect Kt/Vt from overwrite while still in use
        {                  // stage K tile: 32 rows x 64 bf16 = 4096B, 256 thr x 16B
            const int kr = tid >> 3, c8 = tid & 7;
            *(bf16x8*)(Kt + kr * 72 + c8 * 8) =
                *(const bf16x8*)(k + (bh + kt0 + kr) * 64 + c8 * 8);
        }
        {                  // stage V tile transposed: Vt[dh][key]
            const int kr = tid & 31, dg = tid >> 5;
            const bf16x8 tmp = *(const bf16x8*)(v + (bh + kt0 + kr) * 64 + dg * 8);
#pragma unroll
            for (int e = 0; e < 8; ++e)
                Vt[(dg * 8 + e) * 40 + kr] = tmp[e];
        }
        __syncthreads();

        // S = Q K^T : two 16-key halves, dh=64 via 2 chained MFMAs each
        const bf16x8 b00 = *(const bf16x8*)(Kt + m * 72 + quad * 8);
        const bf16x8 b01 = *(const bf16x8*)(Kt + m * 72 + 32 + quad * 8);
        const bf16x8 b10 = *(const bf16x8*)(Kt + (m + 16) * 72 + quad * 8);
        const bf16x8 b11 = *(const bf16x8*)(Kt + (m + 16) * 72 + 32 + quad * 8);
        f32x4 s0 = {0.f, 0.f, 0.f, 0.f}, s1 = {0.f, 0.f, 0.f, 0.f};
        s0 = __builtin_amdgcn_mfma_f32_16x16x32_bf16(aq0, b00, s0, 0, 0, 0);
        s0 = __builtin_amdgcn_mfma_f32_16x16x32_bf16(aq1, b01, s0, 0, 0, 0);
        s1 = __builtin_amdgcn_mfma_f32_16x16x32_bf16(aq0, b10, s1, 0, 0, 0);
        s1 = __builtin_amdgcn_mfma_f32_16x16x32_bf16(aq1, b11, s1, 0, 0, 0);

        const float msk0 = -1e9f * (float)idrow[kt0 + m];
        const float msk1 = -1e9f * (float)idrow[kt0 + 16 + m];

        float p0[4], p1[4], alpha[4];
#pragma unroll
        for (int r = 0; r < 4; ++r) {
            const float l0 = (s0[r] + msk0) * 0.125f;
            const float l1 = (s1[r] + msk1) * 0.125f;
            float t = fmaxf(l0, l1);
            t = fmaxf(t, __shfl_xor(t, 1));
            t = fmaxf(t, __shfl_xor(t, 2));
            t = fmaxf(t, __shfl_xor(t, 4));
            t = fmaxf(t, __shfl_xor(t, 8));
            const float mnew = fmaxf(mrow[r], t);
            alpha[r] = __expf(mrow[r] - mnew);
            p0[r] = __expf(l0 - mnew);
            p1[r] = __expf(l1 - mnew);
            float su = p0[r] + p1[r];
            su += __shfl_xor(su, 1);
            su += __shfl_xor(su, 2);
            su += __shfl_xor(su, 4);
            su += __shfl_xor(su, 8);
            lrow[r] = lrow[r] * alpha[r] + su;
            mrow[r] = mnew;
        }
#pragma unroll
        for (int j = 0; j < 4; ++j)
#pragma unroll
            for (int r = 0; r < 4; ++r)
                o[j][r] *= alpha[r];

        // P (C-layout) -> per-wave LDS -> A-layout frag
        short* pw = Pl[wave];
#pragma unroll
        for (int r = 0; r < 4; ++r) {
            pw[(quad * 4 + r) * 40 + m]      = f2bf(p0[r]);
            pw[(quad * 4 + r) * 40 + 16 + m] = f2bf(p1[r]);
        }
        const bf16x8 pa = *(const bf16x8*)(pw + m * 40 + quad * 8);
#pragma unroll
        for (int j = 0; j < 4; ++j) {
            const bf16x8 bv2 = *(const bf16x8*)(Vt + (j * 16 + m) * 40 + quad * 8);
            o[j] = __builtin_amdgcn_mfma_f32_16x16x32_bf16(pa, bv2, o[j], 0, 0, 0);
        }
    }

    // write O / l : out[b, n, h*64 + dh]
#pragma unroll
    for (int r = 0; r < 4; ++r) {
        const float inv = 1.f / lrow[r];
        const int n = q0 + wave * 16 + quad * 4 + r;
        short* op = outp + ((size_t)(b * N_ + n)) * D_ + h * 64 + m;
#pragma unroll
        for (int j = 0; j < 4; ++j)
            op[j * 16] = f2bf(o[j][r] * inv);
    }
}

// ---------------------------------------------------------------------------
extern "C" void kernel_launch(void* const* d_in, const int* in_sizes, int n_in,
                              void* d_out, int out_size, void* d_ws, size_t ws_size,
                              hipStream_t stream) {
    const float* x   = (const float*)d_in[0];
    const int*   ids = (const int*)d_in[1];
    const float* n1w = (const float*)d_in[2];
    const float* n1b = (const float*)d_in[3];
    const float* win = (const float*)d_in[4];
    const float* wout= (const float*)d_in[5];
    const float* bout= (const float*)d_in[6];
    const float* n2w = (const float*)d_in[7];
    const float* n2b = (const float*)d_in[8];
    const float* w1  = (const float*)d_in[9];
    const float* b1  = (const float*)d_in[10];
    const float* w2  = (const float*)d_in[11];
    const float* b2  = (const float*)d_in[12];
    float* out = (float*)d_out;

    char* ws = (char*)d_ws;
    size_t off = 0;
    auto alloc = [&](size_t bytes) {
        char* p = ws + off;
        off += (bytes + 255) & ~(size_t)255;
        return p;
    };
    short* wq_b = (short*)alloc((size_t)3 * D_ * D_ * 2);       // proj_in bf16
    short* wo_b = (short*)alloc((size_t)D_ * D_ * 2);           // proj_out bf16
    short* w1_b = (short*)alloc((size_t)FF_ * D_ * 2);          // lin1 bf16
    short* w2_b = (short*)alloc((size_t)D_ * FF_ * 2);          // lin2 bf16
    float* xn32 = (float*)alloc((size_t)TOK_ * D_ * 4);         // LN1 out fp32
    short* xnb  = (short*)alloc((size_t)TOK_ * D_ * 2);         // LN1 out bf16
    short* qkv  = (short*)alloc((size_t)3 * TOK_ * D_ * 2);     // q,k,v [B,H,N,64]
    float* x2f  = (float*)alloc((size_t)TOK_ * D_ * 4);         // LN2 out fp32
    short* hbuf = (short*)alloc((size_t)TOK_ * FF_ * 2);        // gelu(lin1) bf16
    // aliases (lifetimes disjoint in stream order):
    short* attno = xnb;          // attention output bf16 (xn_bf16 dead after QKV gemm)
    float* x1f   = (float*)qkv;  // x1 fp32 (qkv dead after attention)
    short* x2b   = xnb;          // LN2 bf16 (attno dead after proj_out gemm)

    // 1) weights -> bf16
    cvt_bf16<<<3 * D_ * D_ / 1024, 256, 0, stream>>>(win, wq_b);
    cvt_bf16<<<D_ * D_ / 1024, 256, 0, stream>>>(wout, wo_b);
    cvt_bf16<<<FF_ * D_ / 1024, 256, 0, stream>>>(w1, w1_b);
    cvt_bf16<<<FF_ * D_ / 1024, 256, 0, stream>>>(w2, w2_b);
    // 2) LN1
    ln_kernel<<<TOK_, 256, 0, stream>>>(x, n1w, n1b, xn32, xnb);
    // 3) QKV projection (scatter epilogue)
    gemm_bt<0><<<dim3(3 * D_ / 128, TOK_ / 128), 256, 0, stream>>>(
        xnb, wq_b, nullptr, nullptr, qkv, TOK_, 3 * D_, D_);
    // 4) attention
    attn_kernel<<<dim3(N_ / 64, H_, B_), 256, 0, stream>>>(
        qkv, qkv + (size_t)TOK_ * D_, qkv + (size_t)2 * TOK_ * D_, ids, attno);
    // 5) out projection + bias + residual(xn) -> x1 fp32
    gemm_bt<1><<<dim3(D_ / 128, TOK_ / 128), 256, 0, stream>>>(
        attno, wo_b, bout, xn32, x1f, TOK_, D_, D_);
    // 6) LN2
    ln_kernel<<<TOK_, 256, 0, stream>>>(x1f, n2w, n2b, x2f, x2b);
    // 7) lin1 + bias + GELU -> h bf16
    gemm_bt<2><<<dim3(FF_ / 128, TOK_ / 128), 256, 0, stream>>>(
        x2b, w1_b, b1, nullptr, hbuf, TOK_, FF_, D_);
    // 8) lin2 + bias + residual(x2) -> out fp32
    gemm_bt<1><<<dim3(D_ / 128, TOK_ / 128), 256, 0, stream>>>(
        hbuf, w2_b, b2, x2f, out, TOK_, D_, FF_);
}